// Round 2
// 409.652 us; speedup vs baseline: 1.0586x; 1.0586x over previous
//
#include <hip/hip_runtime.h>
#include <hip/hip_bf16.h>

typedef __hip_bfloat16 bf16;
typedef __attribute__((ext_vector_type(8))) short short8;
typedef __attribute__((ext_vector_type(4))) float f32x4;

static __device__ __forceinline__ float b2f(bf16 v) { return __bfloat162float(v); }

static __device__ __forceinline__ float ldin(const void* p, long i, int bf) {
    return bf ? b2f(((const bf16*)p)[i]) : ((const float*)p)[i];
}

// ---------------- dtype detect ----------------
__global__ void detect_k(const unsigned short* __restrict__ x16, int* __restrict__ flag) {
    __shared__ int cnt[256];
    unsigned short u = x16[threadIdx.x];
    int e = (u >> 7) & 0xFF;
    cnt[threadIdx.x] = (e >= 100 && e <= 140) ? 1 : 0;
    __syncthreads();
    for (int off = 128; off > 0; off >>= 1) {
        if (threadIdx.x < off) cnt[threadIdx.x] += cnt[threadIdx.x + off];
        __syncthreads();
    }
    if (threadIdx.x == 0) *flag = (cnt[0] > 217) ? 1 : 0;
}

// ---------------- casts / transposes ----------------
__global__ void cast_bf_k(const void* __restrict__ in, bf16* __restrict__ out,
                          int n, const int* __restrict__ flagp) {
    int bf = *flagp;
    int idx = blockIdx.x * 256 + threadIdx.x;
    if (idx >= n) return;
    out[idx] = __float2bfloat16(ldin(in, idx, bf));
}

// w3b[n][h3][c] (bf16) from w3[(h3*256+c)*32+n]
__global__ __launch_bounds__(256) void transpose_w3b_k(const void* __restrict__ w3,
                                                       bf16* __restrict__ out,
                                                       const int* __restrict__ flagp) {
    int bf = *flagp;
    int h3 = blockIdx.x;     // 512
    __shared__ bf16 t[8192];
    long base = (long)h3 * 8192;
    for (int i = threadIdx.x; i < 8192; i += 256)
        t[i] = __float2bfloat16(ldin(w3, base + i, bf));
    __syncthreads();
    for (int i = threadIdx.x; i < 8192; i += 256) {
        int n = i >> 8, c = i & 255;
        out[((long)n * 512 + h3) * 256 + c] = t[c * 32 + n];
    }
}

// hbT[b][tau][c] (bf16) from h[b][c][tau] (fp32)
__global__ void cast_hT_k(const float* __restrict__ h, bf16* __restrict__ out) {
    int idx = blockIdx.x * 256 + threadIdx.x;   // 131072
    if (idx >= 131072) return;
    int b = idx >> 16, r = idx & 65535;
    int tau = r >> 8, c = r & 255;
    out[idx] = __float2bfloat16(h[b * 65536 + c * 256 + tau]);
}

// yT[b][p][c] (bf16) from y[b][c=512][p=2048] (fp32), 64x64 LDS tile
__global__ __launch_bounds__(256) void castT_k(const float* __restrict__ y,
                                               bf16* __restrict__ yT) {
    int p0 = blockIdx.x * 64, c0 = blockIdx.y * 64, b = blockIdx.z;
    __shared__ bf16 t[64][65];
    const float* src = y + (long)b * 1048576;
    for (int i = threadIdx.x; i < 4096; i += 256) {
        int cl = i >> 6, pl = i & 63;
        t[pl][cl] = __float2bfloat16(src[(long)(c0 + cl) * 2048 + p0 + pl]);
    }
    __syncthreads();
    bf16* dst = yT + (long)b * 1048576;
    for (int i = threadIdx.x; i < 4096; i += 256) {
        int pl = i >> 6, cl = i & 63;
        dst[(long)(p0 + pl) * 512 + c0 + cl] = t[pl][cl];
    }
}

// ---------------- bf16 im2col ----------------
__global__ void im2col_xb_k(const void* __restrict__ x, bf16* __restrict__ out,
                            const int* __restrict__ flagp) {
    int bf = *flagp;
    int idx = blockIdx.x * 256 + threadIdx.x;   // 786432
    if (idx >= 786432) return;
    int b = idx / 393216;
    int rem = idx - b * 393216;
    int t = rem / 1536, k = rem - t * 1536;
    int c = k / 3, q = k - c * 3;
    int tt = t + q - 1;
    float v = (tt >= 0 && tt < 256) ? ldin(x, ((long)b * 512 + c) * 256 + tt, bf) : 0.f;
    out[idx] = __float2bfloat16(v);
}

__global__ void im2col_fb_k(const float* __restrict__ f, bf16* __restrict__ out) {
    int idx = blockIdx.x * 256 + threadIdx.x;   // 4718592
    if (idx >= 4718592) return;
    int b = idx / 2359296;
    int rem = idx - b * 2359296;
    int p = rem / 1152, k = rem - p * 1152;
    int c = k / 9, q = k - c * 9;
    int dy = q / 3, dx = q - dy * 3;
    int t = p >> 3, w = p & 7;
    int tt = t + dy - 1, ww = w + dx - 1;
    float v = (tt >= 0 && tt < 256 && ww >= 0 && ww < 8)
                  ? f[((long)b * 128 + c) * 2048 + tt * 8 + ww] : 0.f;
    out[idx] = __float2bfloat16(v);
}

// ---------------- generic weight-GEMM via MFMA ----------------
template<int NT>
__global__ __launch_bounds__(256) void wgemm_mfma(
    const bf16* __restrict__ A, const bf16* __restrict__ B, float* __restrict__ C,
    const void* __restrict__ bias1, const void* __restrict__ bias2,
    int M, int K, int P, int a_div, long a_zs, const int* __restrict__ flagp)
{
    int bf = *flagp;
    int z = blockIdx.z;
    const bf16* A2 = A + (long)(z / a_div) * a_zs;
    const bf16* B2 = B + (long)(z & 1) * (long)P * K;
    float* C2 = C + (long)z * M * P;
    const void* bi = (z / a_div) ? bias2 : bias1;

    int tid = threadIdx.x;
    int wv = tid >> 6, lane = tid & 63;
    int q = lane >> 4, col = lane & 15;
    int m0 = blockIdx.y * 64 + wv * 16;
    int p0 = blockIdx.x * (16 * NT);

    f32x4 acc[NT];
    #pragma unroll
    for (int i = 0; i < NT; ++i) acc[i] = (f32x4){0.f, 0.f, 0.f, 0.f};

    const short8* Ab = (const short8*)(A2 + (long)(m0 + col) * K);
    int kch = K >> 5;
    for (int kc = 0; kc < kch; ++kc) {
        short8 af = Ab[kc * 4 + q];
        #pragma unroll
        for (int nt = 0; nt < NT; ++nt) {
            const short8* Bb = (const short8*)(B2 + (long)(p0 + nt * 16 + col) * K);
            short8 bfr = Bb[kc * 4 + q];
            acc[nt] = __builtin_amdgcn_mfma_f32_16x16x32_bf16(af, bfr, acc[nt], 0, 0, 0);
        }
    }

    float bv[4];
    #pragma unroll
    for (int r = 0; r < 4; ++r) bv[r] = ldin(bi, m0 + q * 4 + r, bf);
    #pragma unroll
    for (int nt = 0; nt < NT; ++nt)
        #pragma unroll
        for (int r = 0; r < 4; ++r)
            C2[(long)(m0 + q * 4 + r) * P + p0 + nt * 16 + col] = acc[nt][r] + bv[r];
}

// ---------------- MFMA P-GEMM ----------------
__global__ __launch_bounds__(256) void pgemm_mfma(
    const bf16* __restrict__ w3b, const bf16* __restrict__ hbT,
    float* __restrict__ P)
{
    int z = blockIdx.z;          // b*32 + n
    int b = z >> 5, n = z & 31;
    int bm = blockIdx.y;         // 0..7
    int tid = threadIdx.x;
    int wv = tid >> 6, lane = tid & 63;
    int q = lane >> 4, col = lane & 15;

    f32x4 acc[16];
    #pragma unroll
    for (int i = 0; i < 16; ++i) acc[i] = (f32x4){0.f, 0.f, 0.f, 0.f};

    const short8* Abase = (const short8*)(w3b + ((long)n * 512 + bm * 64 + wv * 16 + col) * 256);
    const short8* Bbase = (const short8*)(hbT + (long)b * 65536);

    #pragma unroll
    for (int kc = 0; kc < 8; ++kc) {
        short8 af = Abase[kc * 4 + q];
        #pragma unroll
        for (int nt = 0; nt < 16; ++nt) {
            short8 bfr = Bbase[(nt * 16 + col) * 32 + kc * 4 + q];
            acc[nt] = __builtin_amdgcn_mfma_f32_16x16x32_bf16(af, bfr, acc[nt], 0, 0, 0);
        }
    }

    long dbase = (long)b * 4194304 + (long)n * 256 +
                 (long)(bm * 64 + wv * 16 + q * 4) * 8192 + col;
    #pragma unroll
    for (int nt = 0; nt < 16; ++nt)
        #pragma unroll
        for (int r = 0; r < 4; ++r)
            P[dbase + (long)r * 8192 + nt * 16] = acc[nt][r];
}

// ---------------- GroupNorm: single-kernel (small) ----------------
__global__ __launch_bounds__(1024) void gn_relu_k(
    float* __restrict__ buf, const void* __restrict__ g, const void* __restrict__ bt,
    int C, int S, int groups, const int* __restrict__ flagp)
{
    int bf = *flagp;
    int nt = blockDim.x;
    int gid = blockIdx.x;
    int b = gid / groups, gr = gid % groups;
    int cpg = C / groups;
    long cnt = (long)cpg * S;
    float* base = buf + ((long)b * C + (long)gr * cpg) * S;
    double s = 0.0, s2 = 0.0;
    for (long i = threadIdx.x; i < cnt; i += nt) {
        float v = base[i];
        s += v; s2 += (double)v * v;
    }
    __shared__ double rs[1024], rq[1024];
    rs[threadIdx.x] = s; rq[threadIdx.x] = s2;
    __syncthreads();
    for (int off = nt >> 1; off > 0; off >>= 1) {
        if (threadIdx.x < off) { rs[threadIdx.x] += rs[threadIdx.x + off]; rq[threadIdx.x] += rq[threadIdx.x + off]; }
        __syncthreads();
    }
    double mean_d = rs[0] / (double)cnt;
    float mean = (float)mean_d;
    float var = (float)(rq[0] / (double)cnt - mean_d * mean_d);
    float rstd = rsqrtf(var + 1e-5f);
    for (long i = threadIdx.x; i < cnt; i += nt) {
        int c = gr * cpg + (int)(i / S);
        float v = (base[i] - mean) * rstd * ldin(g, c, bf) + ldin(bt, c, bf);
        base[i] = v > 0.f ? v : 0.f;
    }
}

// ---------------- GroupNorm: two-phase (large) ----------------
__global__ __launch_bounds__(256) void gn_part_k(
    const float* __restrict__ buf, double* __restrict__ part,
    int C, int S, int groups, int chunks)
{
    int gi = blockIdx.x / chunks, ch = blockIdx.x % chunks;
    int b = gi / groups, gr = gi % groups;
    int cpg = C / groups;
    long cnt = (long)cpg * S;
    long clen = cnt / chunks;
    const float* base = buf + ((long)b * C + (long)gr * cpg) * S + (long)ch * clen;
    double s = 0.0, s2 = 0.0;
    for (long i = threadIdx.x; i < clen; i += 256) {
        float v = base[i];
        s += v; s2 += (double)v * v;
    }
    __shared__ double rs[256], rq[256];
    rs[threadIdx.x] = s; rq[threadIdx.x] = s2;
    __syncthreads();
    for (int off = 128; off > 0; off >>= 1) {
        if (threadIdx.x < off) { rs[threadIdx.x] += rs[threadIdx.x + off]; rq[threadIdx.x] += rq[threadIdx.x + off]; }
        __syncthreads();
    }
    if (threadIdx.x == 0) { part[blockIdx.x * 2] = rs[0]; part[blockIdx.x * 2 + 1] = rq[0]; }
}

__global__ __launch_bounds__(256) void gn_apply_k(
    float* __restrict__ buf, const double* __restrict__ part,
    const void* __restrict__ g, const void* __restrict__ bt,
    int C, int S, int groups, int chunks, const int* __restrict__ flagp)
{
    int bf = *flagp;
    int gi = blockIdx.x / chunks, ch = blockIdx.x % chunks;
    int b = gi / groups, gr = gi % groups;
    int cpg = C / groups;
    long cnt = (long)cpg * S;
    long clen = cnt / chunks;
    double s = 0.0, s2 = 0.0;
    for (int k = 0; k < chunks; ++k) {
        s += part[(gi * chunks + k) * 2];
        s2 += part[(gi * chunks + k) * 2 + 1];
    }
    double mean_d = s / (double)cnt;
    float mean = (float)mean_d;
    float var = (float)(s2 / (double)cnt - mean_d * mean_d);
    float rstd = rsqrtf(var + 1e-5f);
    float* base = buf + ((long)b * C + (long)gr * cpg) * S + (long)ch * clen;
    long off0 = (long)ch * clen;
    for (long i = threadIdx.x; i < clen; i += 256) {
        int c = gr * cpg + (int)((off0 + i) / S);
        float v = (base[i] - mean) * rstd * ldin(g, c, bf) + ldin(bt, c, bf);
        base[i] = v > 0.f ? v : 0.f;
    }
}

// ---------------- sparse mask table ----------------
__global__ __launch_bounds__(384) void build_table_k(
    const void* __restrict__ mask, int* __restrict__ tabd,
    float* __restrict__ tabw, const int* __restrict__ flagp)
{
    int bf = *flagp;
    int nw = blockIdx.x;
    int w = nw >> 5, n = nw & 31;
    int tid = threadIdx.x;
    int d = tid - 165;
    float v = 0.f;
    if (d <= 165) {
        if (d < 0) v = ldin(mask, (long)(254 + d) * 65536 + ((long)n * 256 + 254) * 8 + w, bf);
        else       v = ldin(mask, (long)(1 + d) * 65536 + ((long)n * 256 + 1) * 8 + w, bf);
    }
    __shared__ unsigned char nz[384];
    nz[tid] = (v != 0.f) ? 1 : 0;
    if (tid < 6) { tabd[nw * 6 + tid] = 0; tabw[nw * 6 + tid] = 0.f; }
    __syncthreads();
    if (v != 0.f) {
        int slot = 0;
        for (int j = 0; j < tid; ++j) slot += nz[j];
        if (slot < 6) { tabd[nw * 6 + slot] = d; tabw[nw * 6 + slot] = v; }
    }
}

// corrT[(w*32+n)*256 + t] = mask[tau=0][n,t,w] - (toeplitz approx at tau=0)
__global__ void build_corr_k(const void* __restrict__ mask, const int* __restrict__ tabd,
                             const float* __restrict__ tabw, float* __restrict__ corrT,
                             const int* __restrict__ flagp) {
    int bf = *flagp;
    int idx = blockIdx.x * 256 + threadIdx.x;   // 65536
    if (idx >= 65536) return;
    int e = idx >> 8, t = idx & 255;            // e = w*32+n
    int w = e >> 5, n = e & 31;
    float mv = ldin(mask, ((long)n * 256 + t) * 8 + w, bf);
    float sub = 0.f;
    int base = e * 6;
    for (int k = 0; k < 6; ++k)
        if (tabd[base + k] == -t && tabw[base + k] != 0.f) sub += tabw[base + k];
    corrT[idx] = mv - sub;
}

// ---------------- fused sparse apply ----------------
// One block per h3-pair. Stages {P[b0,h0],P[b0,h1],P[b1,h0],P[b1,h1]} as float4
// per (n,tau) in LDS (3 chunks of 12/12/8 n), accumulates all nonzero taps
// (compact table, uniform early-exit), fuses bias + tau=0 correction, and
// writes y directly via an LDS re-tile for coalesced float4 stores.
__global__ __launch_bounds__(1024) void apply_y2_k(
    const float* __restrict__ P, const int* __restrict__ tabd,
    const float* __restrict__ tabw, const float* __restrict__ corrT,
    float* __restrict__ y, const void* __restrict__ r3b,
    const int* __restrict__ flagp)
{
    int hp = blockIdx.x;            // 0..255 (h3 pair)
    int h0 = hp * 2;
    int tid = threadIdx.x;
    int t = tid & 255;
    int wg = tid >> 8;              // 0..3
    int w0 = wg * 2;                // this thread owns windows w0, w0+1

    __shared__ float4 Pl[12 * 256];   // 48KB; reused as y-staging (32KB) at end
    __shared__ float4 Tab[768];       // 12KB: (wt,d) pairs, 3 float4 per (w,n)
    __shared__ float4 pzv[32];        // P[.,.,n,0] packed (b0h0,b0h1,b1h0,b1h1)

    const float* Pb00 = P + (long)h0 * 8192;
    const float* Pb01 = P + (long)(h0 + 1) * 8192;
    const float* Pb10 = Pb00 + 4194304;
    const float* Pb11 = Pb01 + 4194304;

    // stage the tap table (wt, d-bits) and the tau=0 P column
    float2* tab2 = (float2*)Tab;
    for (int i = tid; i < 1536; i += 1024)
        tab2[i] = make_float2(tabw[i], __int_as_float(tabd[i]));
    if (tid < 32) {
        int n = tid;
        pzv[n] = make_float4(Pb00[n * 256], Pb01[n * 256], Pb10[n * 256], Pb11[n * 256]);
    }

    float4 acc0 = make_float4(0.f, 0.f, 0.f, 0.f);
    float4 acc1 = make_float4(0.f, 0.f, 0.f, 0.f);

    int cn0 = 0;
    #pragma unroll 1
    for (int ch = 0; ch < 3; ++ch) {
        int NC = (ch == 2) ? 8 : 12;
        __syncthreads();            // previous chunk's readers done (no-op on ch0)
        for (int pos = tid; pos < NC * 256; pos += 1024) {
            int nl = pos >> 8, tau = pos & 255;
            long o = (long)(cn0 + nl) * 256 + tau;
            Pl[pos] = make_float4(Pb00[o], Pb01[o], Pb10[o], Pb11[o]);
        }
        __syncthreads();

        #pragma unroll 1
        for (int nl = 0; nl < NC; ++nl) {
            const float4* Pn = Pl + (nl << 8);
            auto tap = [&](float wt, float df, float4& acc) {
                int d = __float_as_int(df);
                int tau = t + d;
                float wtk = ((unsigned)tau < 256u) ? wt : 0.f;
                float4 pv = Pn[tau & 255];
                acc.x += wtk * pv.x; acc.y += wtk * pv.y;
                acc.z += wtk * pv.z; acc.w += wtk * pv.w;
            };
            int e0 = w0 * 32 + cn0 + nl;
            {   // w = w0
                float4 q0 = Tab[e0 * 3], q1 = Tab[e0 * 3 + 1], q2 = Tab[e0 * 3 + 2];
                if (q0.x != 0.f) { tap(q0.x, q0.y, acc0);
                 if (q0.z != 0.f) { tap(q0.z, q0.w, acc0);
                  if (q1.x != 0.f) { tap(q1.x, q1.y, acc0);
                   if (q1.z != 0.f) { tap(q1.z, q1.w, acc0);
                    if (q2.x != 0.f) { tap(q2.x, q2.y, acc0);
                     if (q2.z != 0.f) { tap(q2.z, q2.w, acc0); }}}}}}
            }
            {   // w = w0+1
                int e1 = e0 + 32;
                float4 q0 = Tab[e1 * 3], q1 = Tab[e1 * 3 + 1], q2 = Tab[e1 * 3 + 2];
                if (q0.x != 0.f) { tap(q0.x, q0.y, acc1);
                 if (q0.z != 0.f) { tap(q0.z, q0.w, acc1);
                  if (q1.x != 0.f) { tap(q1.x, q1.y, acc1);
                   if (q1.z != 0.f) { tap(q1.z, q1.w, acc1);
                    if (q2.x != 0.f) { tap(q2.x, q2.y, acc1);
                     if (q2.z != 0.f) { tap(q2.z, q2.w, acc1); }}}}}}
            }
        }
        cn0 += NC;
    }

    __syncthreads();   // all Pl tap reads done before reuse

    // bias (r3d bias, fused from old merge)
    int bf = *flagp;
    float g0 = ldin(r3b, h0, bf), g1 = ldin(r3b, h0 + 1, bf);
    acc0.x += g0; acc0.y += g1; acc0.z += g0; acc0.w += g1;
    acc1.x += g0; acc1.y += g1; acc1.z += g0; acc1.w += g1;

    // tau=0 correction: acc += P[b,h,n,0] * corrT[w][n][t]  (coalesced in t)
    const float* cT0 = corrT + (long)w0 * 8192 + t;
    const float* cT1 = cT0 + 8192;
    #pragma unroll 4
    for (int n = 0; n < 32; ++n) {
        float4 pz = pzv[n];
        float c0 = cT0[n * 256], c1 = cT1[n * 256];
        acc0.x += c0 * pz.x; acc0.y += c0 * pz.y;
        acc0.z += c0 * pz.z; acc0.w += c0 * pz.w;
        acc1.x += c1 * pz.x; acc1.y += c1 * pz.y;
        acc1.z += c1 * pz.z; acc1.w += c1 * pz.w;
    }

    // re-tile through LDS for coalesced float4 global stores
    float* yb = (float*)Pl;     // 4 x 2048 floats = 32KB
    *(float2*)&yb[0 * 2048 + t * 8 + w0] = make_float2(acc0.x, acc1.x);
    *(float2*)&yb[1 * 2048 + t * 8 + w0] = make_float2(acc0.y, acc1.y);
    *(float2*)&yb[2 * 2048 + t * 8 + w0] = make_float2(acc0.z, acc1.z);
    *(float2*)&yb[3 * 2048 + t * 8 + w0] = make_float2(acc0.w, acc1.w);
    __syncthreads();
    for (int f = tid; f < 2048; f += 1024) {
        int c = f >> 9, r = f & 511;
        int tt = r >> 1, half = r & 1;
        float4 v = *(const float4*)&yb[c * 2048 + tt * 8 + half * 4];
        int b = c >> 1, hh = h0 + (c & 1);
        *(float4*)&y[((long)b * 512 + hh) * 2048 + tt * 8 + half * 4] = v;
    }
}

__global__ __launch_bounds__(64) void head_out_k(
    const float* __restrict__ t1s, const float* __restrict__ t1e,
    const void* __restrict__ s2w, const void* __restrict__ s2b,
    const void* __restrict__ e2w, const void* __restrict__ e2b,
    void* __restrict__ out, const int* __restrict__ flagp) {
    int bf = *flagp;
    int idx = blockIdx.x * 64 + threadIdx.x;   // 4096
    if (idx >= 4096) return;
    int b = idx >> 11, p = idx & 2047;
    const float* ts = t1s + (long)b * 262144 + p;
    const float* te = t1e + (long)b * 262144 + p;
    float as = ldin(s2b, 0, bf), ae = ldin(e2b, 0, bf);
    #pragma unroll 8
    for (int c = 0; c < 128; ++c) {
        as += ldin(s2w, c, bf) * ts[(long)c * 2048];
        ae += ldin(e2w, c, bf) * te[(long)c * 2048];
    }
    float vs = 1.f / (1.f + expf(-as));
    float ve = 1.f / (1.f + expf(-ae));
    long o0 = ((long)b * 2) * 2048 + p;
    long o1 = ((long)b * 2 + 1) * 2048 + p;
    if (bf) {
        ((bf16*)out)[o0] = __float2bfloat16(vs);
        ((bf16*)out)[o1] = __float2bfloat16(ve);
    } else {
        ((float*)out)[o0] = vs;
        ((float*)out)[o1] = ve;
    }
}

// ---------------- launch ----------------
extern "C" void kernel_launch(void* const* d_in, const int* in_sizes, int n_in,
                              void* d_out, int out_size, void* d_ws, size_t ws_size,
                              hipStream_t stream) {
    const void* x    = d_in[0];
    const void* mask = d_in[1];
    const void* c1w  = d_in[2];
    const void* c1b  = d_in[3];
    const void* gn1g = d_in[4];
    const void* gn1b = d_in[5];
    const void* w3   = d_in[6];
    const void* r3b  = d_in[7];
    const void* gn3g = d_in[8];
    const void* gn3b = d_in[9];
    const void* w2   = d_in[10];
    const void* r2b  = d_in[11];
    const void* gn2g = d_in[12];
    const void* gn2b = d_in[13];
    const void* s1w  = d_in[14];
    const void* s1b  = d_in[15];
    const void* sgng = d_in[16];
    const void* sgnb = d_in[17];
    const void* s2w  = d_in[18];
    const void* s2b  = d_in[19];
    const void* e1w  = d_in[20];
    const void* e1b  = d_in[21];
    const void* egng = d_in[22];
    const void* egnb = d_in[23];
    const void* e2w  = d_in[24];
    const void* e2b  = d_in[25];
    float* ws = (float*)d_ws;

    int*   flagI = (int*)(ws + 0);       // 64 reserved
    float* h     = ws + 64;              // 131072
    float* c1t   = ws + 131136;          // 393216 (c1wb bf16)
    float* w2t   = ws + 524352;          // 65536 (w2b bf16)
    float* s1t   = ws + 589888;          // 294912 (s1wb+e1wb bf16)
    float* corrB = ws + 884800;          // 65536 (corrT layout [w][n][t])
    float* tabw  = ws + 950336;          // 1536
    int*   tabd  = (int*)(ws + 951872);  // 1536
    float* t1s   = ws + 986176;          // 524288
    float* t1e   = ws + 1510464;         // 524288
    float* f     = ws + 2034752;         // 524288
    float* y     = ws + 2559040;         // 2097152
    float* w3reg = ws + 4656192;         // 4194304 (bf16 bufs)
    float* Pb    = ws + 8850496;         // 8388608
    double* gnbuf = (double*)(ws + 17239104); // 1024 doubles
    bf16*  w3b   = (bf16*)w3reg;
    bf16*  hbT   = (bf16*)(w3reg + 2097152);
    bf16*  c1wb  = (bf16*)c1t;
    bf16*  w2b   = (bf16*)w2t;
    bf16*  hwb   = (bf16*)s1t;
    bf16*  colxb = (bf16*)y;                       // y dead until apply
    bf16*  fcolb = (bf16*)Pb;                      // Pb[0..2.36M floats) post-apply
    bf16*  yT    = (bf16*)(Pb + 4194304);          // Pb tail (P dead post-apply)

    dim3 blk(256);
    dim3 blkG(1024);

    detect_k<<<dim3(1), blk, 0, stream>>>((const unsigned short*)x, flagI);

    // weight prep + table extraction
    cast_bf_k<<<dim3(1536), blk, 0, stream>>>(c1w, c1wb, 393216, flagI);
    cast_bf_k<<<dim3(576),  blk, 0, stream>>>(s1w, hwb, 147456, flagI);
    cast_bf_k<<<dim3(576),  blk, 0, stream>>>(e1w, hwb + 147456, 147456, flagI);
    cast_bf_k<<<dim3(256),  blk, 0, stream>>>(w2, w2b, 65536, flagI);
    transpose_w3b_k<<<dim3(512), blk, 0, stream>>>(w3, w3b, flagI);
    build_table_k<<<dim3(256), dim3(384), 0, stream>>>(mask, tabd, tabw, flagI);
    build_corr_k<<<dim3(256), blk, 0, stream>>>(mask, tabd, tabw, corrB, flagI);

    // conv1 via MFMA + GN1 + ReLU
    im2col_xb_k<<<dim3(3072), blk, 0, stream>>>(x, colxb, flagI);
    wgemm_mfma<1><<<dim3(16, 4, 2), blk, 0, stream>>>(
        c1wb, colxb, h, c1b, c1b, 256, 1536, 256, 1, 0L, flagI);
    gn_relu_k<<<dim3(64), blkG, 0, stream>>>(h, gn1g, gn1b, 256, 256, 32, flagI);

    // P-GEMM via bf16 MFMA
    cast_hT_k<<<dim3(512), blk, 0, stream>>>(h, hbT);
    pgemm_mfma<<<dim3(1, 8, 64), blk, 0, stream>>>(w3b, hbT, Pb);

    // fused sparse apply (taps + bias + corr -> y) + GN3 (2-phase)
    apply_y2_k<<<dim3(256), dim3(1024), 0, stream>>>(Pb, tabd, tabw, corrB, y, r3b, flagI);
    gn_part_k<<<dim3(512), blk, 0, stream>>>(y, gnbuf, 512, 2048, 32, 8);
    gn_apply_k<<<dim3(512), blk, 0, stream>>>(y, gnbuf, gn3g, gn3b, 512, 2048, 32, 8, flagI);

    // r2d via MFMA: cast-transpose y -> yT bf16, wgemm (bias fused) + GN2 (2-phase)
    castT_k<<<dim3(32, 8, 2), blk, 0, stream>>>(y, yT);
    wgemm_mfma<2><<<dim3(64, 2, 2), blk, 0, stream>>>(
        w2b, yT, f, r2b, r2b, 128, 512, 2048, 2, 0L, flagI);
    gn_part_k<<<dim3(256), blk, 0, stream>>>(f, gnbuf, 128, 2048, 32, 4);
    gn_apply_k<<<dim3(256), blk, 0, stream>>>(f, gnbuf, gn2g, gn2b, 128, 2048, 32, 4, flagI);

    // heads via MFMA + GN (2-phase each)
    im2col_fb_k<<<dim3(18432), blk, 0, stream>>>(f, fcolb);
    wgemm_mfma<4><<<dim3(32, 2, 4), blk, 0, stream>>>(
        hwb, fcolb, t1s, s1b, e1b, 128, 1152, 2048, 2, 147456L, flagI);
    gn_part_k<<<dim3(256), blk, 0, stream>>>(t1s, gnbuf, 128, 2048, 32, 4);
    gn_apply_k<<<dim3(256), blk, 0, stream>>>(t1s, gnbuf, sgng, sgnb, 128, 2048, 32, 4, flagI);
    gn_part_k<<<dim3(256), blk, 0, stream>>>(t1e, gnbuf, 128, 2048, 32, 4);
    gn_apply_k<<<dim3(256), blk, 0, stream>>>(t1e, gnbuf, egng, egnb, 128, 2048, 32, 4, flagI);

    // 1x1 head convs + sigmoid -> output
    head_out_k<<<dim3(64), dim3(64), 0, stream>>>(t1s, t1e, s2w, s2b, e2w, e2b, d_out, flagI);
}

// Round 3
// 389.621 us; speedup vs baseline: 1.1131x; 1.0514x over previous
//
#include <hip/hip_runtime.h>
#include <hip/hip_bf16.h>

typedef __hip_bfloat16 bf16;
typedef __attribute__((ext_vector_type(8))) short short8;
typedef __attribute__((ext_vector_type(4))) float f32x4;

static __device__ __forceinline__ float b2f(bf16 v) { return __bfloat162float(v); }

static __device__ __forceinline__ float ldin(const void* p, long i, int bf) {
    return bf ? b2f(((const bf16*)p)[i]) : ((const float*)p)[i];
}

// ---------------- dtype detect ----------------
__global__ void detect_k(const unsigned short* __restrict__ x16, int* __restrict__ flag) {
    __shared__ int cnt[256];
    unsigned short u = x16[threadIdx.x];
    int e = (u >> 7) & 0xFF;
    cnt[threadIdx.x] = (e >= 100 && e <= 140) ? 1 : 0;
    __syncthreads();
    for (int off = 128; off > 0; off >>= 1) {
        if (threadIdx.x < off) cnt[threadIdx.x] += cnt[threadIdx.x + off];
        __syncthreads();
    }
    if (threadIdx.x == 0) *flag = (cnt[0] > 217) ? 1 : 0;
}

// ---------------- casts / transposes ----------------
__global__ void cast_bf_k(const void* __restrict__ in, bf16* __restrict__ out,
                          int n, const int* __restrict__ flagp) {
    int bf = *flagp;
    int idx = blockIdx.x * 256 + threadIdx.x;
    if (idx >= n) return;
    out[idx] = __float2bfloat16(ldin(in, idx, bf));
}

// w3b[n][h3][c] (bf16) from w3[(h3*256+c)*32+n]
__global__ __launch_bounds__(256) void transpose_w3b_k(const void* __restrict__ w3,
                                                       bf16* __restrict__ out,
                                                       const int* __restrict__ flagp) {
    int bf = *flagp;
    int h3 = blockIdx.x;     // 512
    __shared__ bf16 t[8192];
    long base = (long)h3 * 8192;
    for (int i = threadIdx.x; i < 8192; i += 256)
        t[i] = __float2bfloat16(ldin(w3, base + i, bf));
    __syncthreads();
    for (int i = threadIdx.x; i < 8192; i += 256) {
        int n = i >> 8, c = i & 255;
        out[((long)n * 512 + h3) * 256 + c] = t[c * 32 + n];
    }
}

// hbT[b][tau][c] (bf16) from h[b][c][tau] (fp32)
__global__ void cast_hT_k(const float* __restrict__ h, bf16* __restrict__ out) {
    int idx = blockIdx.x * 256 + threadIdx.x;   // 131072
    if (idx >= 131072) return;
    int b = idx >> 16, r = idx & 65535;
    int tau = r >> 8, c = r & 255;
    out[idx] = __float2bfloat16(h[b * 65536 + c * 256 + tau]);
}

// yT[b][p][c] (bf16) from y[b][c=512][p=2048] (fp32), 64x64 LDS tile
__global__ __launch_bounds__(256) void castT_k(const float* __restrict__ y,
                                               bf16* __restrict__ yT) {
    int p0 = blockIdx.x * 64, c0 = blockIdx.y * 64, b = blockIdx.z;
    __shared__ bf16 t[64][65];
    const float* src = y + (long)b * 1048576;
    for (int i = threadIdx.x; i < 4096; i += 256) {
        int cl = i >> 6, pl = i & 63;
        t[pl][cl] = __float2bfloat16(src[(long)(c0 + cl) * 2048 + p0 + pl]);
    }
    __syncthreads();
    bf16* dst = yT + (long)b * 1048576;
    for (int i = threadIdx.x; i < 4096; i += 256) {
        int pl = i >> 6, cl = i & 63;
        dst[(long)(p0 + pl) * 512 + c0 + cl] = t[pl][cl];
    }
}

// ---------------- bf16 im2col ----------------
__global__ void im2col_xb_k(const void* __restrict__ x, bf16* __restrict__ out,
                            const int* __restrict__ flagp) {
    int bf = *flagp;
    int idx = blockIdx.x * 256 + threadIdx.x;   // 786432
    if (idx >= 786432) return;
    int b = idx / 393216;
    int rem = idx - b * 393216;
    int t = rem / 1536, k = rem - t * 1536;
    int c = k / 3, q = k - c * 3;
    int tt = t + q - 1;
    float v = (tt >= 0 && tt < 256) ? ldin(x, ((long)b * 512 + c) * 256 + tt, bf) : 0.f;
    out[idx] = __float2bfloat16(v);
}

__global__ void im2col_fb_k(const float* __restrict__ f, bf16* __restrict__ out) {
    int idx = blockIdx.x * 256 + threadIdx.x;   // 4718592
    if (idx >= 4718592) return;
    int b = idx / 2359296;
    int rem = idx - b * 2359296;
    int p = rem / 1152, k = rem - p * 1152;
    int c = k / 9, q = k - c * 9;
    int dy = q / 3, dx = q - dy * 3;
    int t = p >> 3, w = p & 7;
    int tt = t + dy - 1, ww = w + dx - 1;
    float v = (tt >= 0 && tt < 256 && ww >= 0 && ww < 8)
                  ? f[((long)b * 128 + c) * 2048 + tt * 8 + ww] : 0.f;
    out[idx] = __float2bfloat16(v);
}

// ---------------- generic weight-GEMM via MFMA ----------------
template<int NT>
__global__ __launch_bounds__(256) void wgemm_mfma(
    const bf16* __restrict__ A, const bf16* __restrict__ B, float* __restrict__ C,
    const void* __restrict__ bias1, const void* __restrict__ bias2,
    int M, int K, int P, int a_div, long a_zs, const int* __restrict__ flagp)
{
    int bf = *flagp;
    int z = blockIdx.z;
    const bf16* A2 = A + (long)(z / a_div) * a_zs;
    const bf16* B2 = B + (long)(z & 1) * (long)P * K;
    float* C2 = C + (long)z * M * P;
    const void* bi = (z / a_div) ? bias2 : bias1;

    int tid = threadIdx.x;
    int wv = tid >> 6, lane = tid & 63;
    int q = lane >> 4, col = lane & 15;
    int m0 = blockIdx.y * 64 + wv * 16;
    int p0 = blockIdx.x * (16 * NT);

    f32x4 acc[NT];
    #pragma unroll
    for (int i = 0; i < NT; ++i) acc[i] = (f32x4){0.f, 0.f, 0.f, 0.f};

    const short8* Ab = (const short8*)(A2 + (long)(m0 + col) * K);
    int kch = K >> 5;
    for (int kc = 0; kc < kch; ++kc) {
        short8 af = Ab[kc * 4 + q];
        #pragma unroll
        for (int nt = 0; nt < NT; ++nt) {
            const short8* Bb = (const short8*)(B2 + (long)(p0 + nt * 16 + col) * K);
            short8 bfr = Bb[kc * 4 + q];
            acc[nt] = __builtin_amdgcn_mfma_f32_16x16x32_bf16(af, bfr, acc[nt], 0, 0, 0);
        }
    }

    float bv[4];
    #pragma unroll
    for (int r = 0; r < 4; ++r) bv[r] = ldin(bi, m0 + q * 4 + r, bf);
    #pragma unroll
    for (int nt = 0; nt < NT; ++nt)
        #pragma unroll
        for (int r = 0; r < 4; ++r)
            C2[(long)(m0 + q * 4 + r) * P + p0 + nt * 16 + col] = acc[nt][r] + bv[r];
}

// ---------------- GroupNorm: single-kernel (small) ----------------
__global__ __launch_bounds__(1024) void gn_relu_k(
    float* __restrict__ buf, const void* __restrict__ g, const void* __restrict__ bt,
    int C, int S, int groups, const int* __restrict__ flagp)
{
    int bf = *flagp;
    int nt = blockDim.x;
    int gid = blockIdx.x;
    int b = gid / groups, gr = gid % groups;
    int cpg = C / groups;
    long cnt = (long)cpg * S;
    float* base = buf + ((long)b * C + (long)gr * cpg) * S;
    double s = 0.0, s2 = 0.0;
    for (long i = threadIdx.x; i < cnt; i += nt) {
        float v = base[i];
        s += v; s2 += (double)v * v;
    }
    __shared__ double rs[1024], rq[1024];
    rs[threadIdx.x] = s; rq[threadIdx.x] = s2;
    __syncthreads();
    for (int off = nt >> 1; off > 0; off >>= 1) {
        if (threadIdx.x < off) { rs[threadIdx.x] += rs[threadIdx.x + off]; rq[threadIdx.x] += rq[threadIdx.x + off]; }
        __syncthreads();
    }
    double mean_d = rs[0] / (double)cnt;
    float mean = (float)mean_d;
    float var = (float)(rq[0] / (double)cnt - mean_d * mean_d);
    float rstd = rsqrtf(var + 1e-5f);
    for (long i = threadIdx.x; i < cnt; i += nt) {
        int c = gr * cpg + (int)(i / S);
        float v = (base[i] - mean) * rstd * ldin(g, c, bf) + ldin(bt, c, bf);
        base[i] = v > 0.f ? v : 0.f;
    }
}

// ---------------- GroupNorm: two-phase (large) ----------------
__global__ __launch_bounds__(256) void gn_part_k(
    const float* __restrict__ buf, double* __restrict__ part,
    int C, int S, int groups, int chunks)
{
    int gi = blockIdx.x / chunks, ch = blockIdx.x % chunks;
    int b = gi / groups, gr = gi % groups;
    int cpg = C / groups;
    long cnt = (long)cpg * S;
    long clen = cnt / chunks;
    const float* base = buf + ((long)b * C + (long)gr * cpg) * S + (long)ch * clen;
    double s = 0.0, s2 = 0.0;
    for (long i = threadIdx.x; i < clen; i += 256) {
        float v = base[i];
        s += v; s2 += (double)v * v;
    }
    __shared__ double rs[256], rq[256];
    rs[threadIdx.x] = s; rq[threadIdx.x] = s2;
    __syncthreads();
    for (int off = 128; off > 0; off >>= 1) {
        if (threadIdx.x < off) { rs[threadIdx.x] += rs[threadIdx.x + off]; rq[threadIdx.x] += rq[threadIdx.x + off]; }
        __syncthreads();
    }
    if (threadIdx.x == 0) { part[blockIdx.x * 2] = rs[0]; part[blockIdx.x * 2 + 1] = rq[0]; }
}

__global__ __launch_bounds__(256) void gn_apply_k(
    float* __restrict__ buf, const double* __restrict__ part,
    const void* __restrict__ g, const void* __restrict__ bt,
    int C, int S, int groups, int chunks, const int* __restrict__ flagp)
{
    int bf = *flagp;
    int gi = blockIdx.x / chunks, ch = blockIdx.x % chunks;
    int b = gi / groups, gr = gi % groups;
    int cpg = C / groups;
    long cnt = (long)cpg * S;
    long clen = cnt / chunks;
    double s = 0.0, s2 = 0.0;
    for (int k = 0; k < chunks; ++k) {
        s += part[(gi * chunks + k) * 2];
        s2 += part[(gi * chunks + k) * 2 + 1];
    }
    double mean_d = s / (double)cnt;
    float mean = (float)mean_d;
    float var = (float)(s2 / (double)cnt - mean_d * mean_d);
    float rstd = rsqrtf(var + 1e-5f);
    float* base = buf + ((long)b * C + (long)gr * cpg) * S + (long)ch * clen;
    long off0 = (long)ch * clen;
    for (long i = threadIdx.x; i < clen; i += 256) {
        int c = gr * cpg + (int)((off0 + i) / S);
        float v = (base[i] - mean) * rstd * ldin(g, c, bf) + ldin(bt, c, bf);
        base[i] = v > 0.f ? v : 0.f;
    }
}

// ---------------- sparse mask table ----------------
__global__ __launch_bounds__(384) void build_table_k(
    const void* __restrict__ mask, int* __restrict__ tabd,
    float* __restrict__ tabw, const int* __restrict__ flagp)
{
    int bf = *flagp;
    int nw = blockIdx.x;
    int w = nw >> 5, n = nw & 31;
    int tid = threadIdx.x;
    int d = tid - 165;
    float v = 0.f;
    if (d <= 165) {
        if (d < 0) v = ldin(mask, (long)(254 + d) * 65536 + ((long)n * 256 + 254) * 8 + w, bf);
        else       v = ldin(mask, (long)(1 + d) * 65536 + ((long)n * 256 + 1) * 8 + w, bf);
    }
    __shared__ unsigned char nz[384];
    nz[tid] = (v != 0.f) ? 1 : 0;
    if (tid < 6) { tabd[nw * 6 + tid] = 0; tabw[nw * 6 + tid] = 0.f; }
    __syncthreads();
    if (v != 0.f) {
        int slot = 0;
        for (int j = 0; j < tid; ++j) slot += nz[j];
        if (slot < 6) { tabd[nw * 6 + slot] = d; tabw[nw * 6 + slot] = v; }
    }
}

// corrT[(w*32+n)*256 + t] = mask[tau=0][n,t,w] - (toeplitz approx at tau=0)
__global__ void build_corr_k(const void* __restrict__ mask, const int* __restrict__ tabd,
                             const float* __restrict__ tabw, float* __restrict__ corrT,
                             const int* __restrict__ flagp) {
    int bf = *flagp;
    int idx = blockIdx.x * 256 + threadIdx.x;   // 65536
    if (idx >= 65536) return;
    int e = idx >> 8, t = idx & 255;            // e = w*32+n
    int w = e >> 5, n = e & 31;
    float mv = ldin(mask, ((long)n * 256 + t) * 8 + w, bf);
    float sub = 0.f;
    int base = e * 6;
    for (int k = 0; k < 6; ++k)
        if (tabd[base + k] == -t && tabw[base + k] != 0.f) sub += tabw[base + k];
    corrT[idx] = mv - sub;
}

// ---------------- fused P-GEMM + sparse apply ----------------
// One block per h3-pair. The P tile P[b][h0,h1][n][tau] (needed only by this
// block) is computed IN-BLOCK via MFMA from w3b rows and hbT cols, written to
// LDS in the (b*2+h) float4 packing, then consumed by the tap loop. P never
// touches HBM. Two chunks of 16 n (64KB LDS tile each pass).
__global__ __launch_bounds__(1024) void apply_y3_k(
    const bf16* __restrict__ w3b, const bf16* __restrict__ hbT,
    const int* __restrict__ tabd, const float* __restrict__ tabw,
    const float* __restrict__ corrT, float* __restrict__ y,
    const void* __restrict__ r3b, const int* __restrict__ flagp)
{
    int hp = blockIdx.x;            // 0..255 (h3 pair)
    int h0 = hp * 2;
    int tid = threadIdx.x;
    int t = tid & 255;
    int wg = tid >> 8;              // 0..3
    int w0 = wg * 2;                // this thread owns windows w0, w0+1

    int wv = tid >> 6;              // wave 0..15
    int lane = tid & 63;
    int q = lane >> 4, col = lane & 15;

    __shared__ float4 Pl[16 * 256];   // 64KB: chunk of 16 n; reused as y-staging
    __shared__ float4 Tab[768];       // 12KB: (wt,d) pairs, 3 float4 per (w,n)
    __shared__ float4 pzv[32];        // P[.,.,n,0] packed (b0h0,b0h1,b1h0,b1h1)

    // stage the tap table
    float2* tab2 = (float2*)Tab;
    for (int i = tid; i < 1536; i += 1024)
        tab2[i] = make_float2(tabw[i], __int_as_float(tabd[i]));

    // B fragment pointers: col j = wv*32 + ct*16 + col  (j = b*256 + tau)
    const short8* Bb0 = (const short8*)(hbT + (long)(wv * 32 + col) * 256);
    const short8* Bb1 = (const short8*)(hbT + (long)(wv * 32 + 16 + col) * 256);
    int jb = wv * 32 + col;
    int b_ = wv >> 3;               // wave-uniform batch index
    int tau0 = jb & 255;
    int tau1 = (jb + 16) & 255;

    float4 acc0 = make_float4(0.f, 0.f, 0.f, 0.f);
    float4 acc1 = make_float4(0.f, 0.f, 0.f, 0.f);

    #pragma unroll 1
    for (int ch = 0; ch < 2; ++ch) {
        int cn0 = ch * 16;
        __syncthreads();            // prev chunk's tap reads done (no-op on ch0)

        // ---- GEMM phase: rows m=0..31 -> n = cn0 + (m>>1), h = h0 + (m&1) ----
        f32x4 g00 = (f32x4){0.f,0.f,0.f,0.f}, g01 = (f32x4){0.f,0.f,0.f,0.f};
        f32x4 g10 = (f32x4){0.f,0.f,0.f,0.f}, g11 = (f32x4){0.f,0.f,0.f,0.f};
        const short8* Aa0 = (const short8*)(w3b +
            ((long)(cn0 + (col >> 1)) * 512 + h0 + (col & 1)) * 256);
        const short8* Aa1 = (const short8*)(w3b +
            ((long)(cn0 + 8 + (col >> 1)) * 512 + h0 + (col & 1)) * 256);
        #pragma unroll
        for (int kc = 0; kc < 8; ++kc) {
            short8 a0 = Aa0[kc * 4 + q];
            short8 a1 = Aa1[kc * 4 + q];
            short8 b0 = Bb0[kc * 4 + q];
            short8 b1 = Bb1[kc * 4 + q];
            g00 = __builtin_amdgcn_mfma_f32_16x16x32_bf16(a0, b0, g00, 0, 0, 0);
            g01 = __builtin_amdgcn_mfma_f32_16x16x32_bf16(a0, b1, g01, 0, 0, 0);
            g10 = __builtin_amdgcn_mfma_f32_16x16x32_bf16(a1, b0, g10, 0, 0, 0);
            g11 = __builtin_amdgcn_mfma_f32_16x16x32_bf16(a1, b1, g11, 0, 0, 0);
        }
        // fragment rows m = rt*16 + q*4 + r: nl = rt*8 + q*2 + (r>>1), hl = r&1
        // write hl-pairs as float2 at Pl_f[(nl*256+tau)*4 + b_*2]
        float* Plf = (float*)Pl;
        #pragma unroll
        for (int rh = 0; rh < 2; ++rh) {
            int nl0 = q * 2 + rh;
            int nl1 = 8 + q * 2 + rh;
            *(float2*)&Plf[(nl0 * 256 + tau0) * 4 + b_ * 2] = make_float2(g00[2*rh], g00[2*rh+1]);
            *(float2*)&Plf[(nl0 * 256 + tau1) * 4 + b_ * 2] = make_float2(g01[2*rh], g01[2*rh+1]);
            *(float2*)&Plf[(nl1 * 256 + tau0) * 4 + b_ * 2] = make_float2(g10[2*rh], g10[2*rh+1]);
            *(float2*)&Plf[(nl1 * 256 + tau1) * 4 + b_ * 2] = make_float2(g11[2*rh], g11[2*rh+1]);
        }
        __syncthreads();            // P tile visible

        if (tid < 16) pzv[cn0 + tid] = Pl[tid * 256];   // tau=0 column

        // ---- tap phase for this chunk (16 n) ----
        #pragma unroll 1
        for (int nl = 0; nl < 16; ++nl) {
            const float4* Pn = Pl + (nl << 8);
            auto tap = [&](float wt, float df, float4& acc) {
                int d = __float_as_int(df);
                int tau = t + d;
                float wtk = ((unsigned)tau < 256u) ? wt : 0.f;
                float4 pv = Pn[tau & 255];
                acc.x += wtk * pv.x; acc.y += wtk * pv.y;
                acc.z += wtk * pv.z; acc.w += wtk * pv.w;
            };
            int e0 = w0 * 32 + cn0 + nl;
            {   // w = w0
                float4 q0 = Tab[e0 * 3], q1 = Tab[e0 * 3 + 1], q2 = Tab[e0 * 3 + 2];
                if (q0.x != 0.f) { tap(q0.x, q0.y, acc0);
                 if (q0.z != 0.f) { tap(q0.z, q0.w, acc0);
                  if (q1.x != 0.f) { tap(q1.x, q1.y, acc0);
                   if (q1.z != 0.f) { tap(q1.z, q1.w, acc0);
                    if (q2.x != 0.f) { tap(q2.x, q2.y, acc0);
                     if (q2.z != 0.f) { tap(q2.z, q2.w, acc0); }}}}}}
            }
            {   // w = w0+1
                int e1 = e0 + 32;
                float4 q0 = Tab[e1 * 3], q1 = Tab[e1 * 3 + 1], q2 = Tab[e1 * 3 + 2];
                if (q0.x != 0.f) { tap(q0.x, q0.y, acc1);
                 if (q0.z != 0.f) { tap(q0.z, q0.w, acc1);
                  if (q1.x != 0.f) { tap(q1.x, q1.y, acc1);
                   if (q1.z != 0.f) { tap(q1.z, q1.w, acc1);
                    if (q2.x != 0.f) { tap(q2.x, q2.y, acc1);
                     if (q2.z != 0.f) { tap(q2.z, q2.w, acc1); }}}}}}
            }
        }
    }

    __syncthreads();   // all Pl tap reads + pzv writes done before reuse

    // bias (r3d bias)
    int bf = *flagp;
    float g0 = ldin(r3b, h0, bf), g1 = ldin(r3b, h0 + 1, bf);
    acc0.x += g0; acc0.y += g1; acc0.z += g0; acc0.w += g1;
    acc1.x += g0; acc1.y += g1; acc1.z += g0; acc1.w += g1;

    // tau=0 correction: acc += P[b,h,n,0] * corrT[w][n][t]  (coalesced in t)
    const float* cT0 = corrT + (long)w0 * 8192 + t;
    const float* cT1 = cT0 + 8192;
    #pragma unroll 4
    for (int n = 0; n < 32; ++n) {
        float4 pz = pzv[n];
        float c0 = cT0[n * 256], c1 = cT1[n * 256];
        acc0.x += c0 * pz.x; acc0.y += c0 * pz.y;
        acc0.z += c0 * pz.z; acc0.w += c0 * pz.w;
        acc1.x += c1 * pz.x; acc1.y += c1 * pz.y;
        acc1.z += c1 * pz.z; acc1.w += c1 * pz.w;
    }

    // re-tile through LDS for coalesced float4 global stores
    float* yb = (float*)Pl;     // 4 x 2048 floats = 32KB
    *(float2*)&yb[0 * 2048 + t * 8 + w0] = make_float2(acc0.x, acc1.x);
    *(float2*)&yb[1 * 2048 + t * 8 + w0] = make_float2(acc0.y, acc1.y);
    *(float2*)&yb[2 * 2048 + t * 8 + w0] = make_float2(acc0.z, acc1.z);
    *(float2*)&yb[3 * 2048 + t * 8 + w0] = make_float2(acc0.w, acc1.w);
    __syncthreads();
    for (int f = tid; f < 2048; f += 1024) {
        int c = f >> 9, r = f & 511;
        int tt = r >> 1, half = r & 1;
        float4 v = *(const float4*)&yb[c * 2048 + tt * 8 + half * 4];
        int b = c >> 1, hh = h0 + (c & 1);
        *(float4*)&y[((long)b * 512 + hh) * 2048 + tt * 8 + half * 4] = v;
    }
}

__global__ __launch_bounds__(64) void head_out_k(
    const float* __restrict__ t1s, const float* __restrict__ t1e,
    const void* __restrict__ s2w, const void* __restrict__ s2b,
    const void* __restrict__ e2w, const void* __restrict__ e2b,
    void* __restrict__ out, const int* __restrict__ flagp) {
    int bf = *flagp;
    int idx = blockIdx.x * 64 + threadIdx.x;   // 4096
    if (idx >= 4096) return;
    int b = idx >> 11, p = idx & 2047;
    const float* ts = t1s + (long)b * 262144 + p;
    const float* te = t1e + (long)b * 262144 + p;
    float as = ldin(s2b, 0, bf), ae = ldin(e2b, 0, bf);
    #pragma unroll 8
    for (int c = 0; c < 128; ++c) {
        as += ldin(s2w, c, bf) * ts[(long)c * 2048];
        ae += ldin(e2w, c, bf) * te[(long)c * 2048];
    }
    float vs = 1.f / (1.f + expf(-as));
    float ve = 1.f / (1.f + expf(-ae));
    long o0 = ((long)b * 2) * 2048 + p;
    long o1 = ((long)b * 2 + 1) * 2048 + p;
    if (bf) {
        ((bf16*)out)[o0] = __float2bfloat16(vs);
        ((bf16*)out)[o1] = __float2bfloat16(ve);
    } else {
        ((float*)out)[o0] = vs;
        ((float*)out)[o1] = ve;
    }
}

// ---------------- launch ----------------
extern "C" void kernel_launch(void* const* d_in, const int* in_sizes, int n_in,
                              void* d_out, int out_size, void* d_ws, size_t ws_size,
                              hipStream_t stream) {
    const void* x    = d_in[0];
    const void* mask = d_in[1];
    const void* c1w  = d_in[2];
    const void* c1b  = d_in[3];
    const void* gn1g = d_in[4];
    const void* gn1b = d_in[5];
    const void* w3   = d_in[6];
    const void* r3b  = d_in[7];
    const void* gn3g = d_in[8];
    const void* gn3b = d_in[9];
    const void* w2   = d_in[10];
    const void* r2b  = d_in[11];
    const void* gn2g = d_in[12];
    const void* gn2b = d_in[13];
    const void* s1w  = d_in[14];
    const void* s1b  = d_in[15];
    const void* sgng = d_in[16];
    const void* sgnb = d_in[17];
    const void* s2w  = d_in[18];
    const void* s2b  = d_in[19];
    const void* e1w  = d_in[20];
    const void* e1b  = d_in[21];
    const void* egng = d_in[22];
    const void* egnb = d_in[23];
    const void* e2w  = d_in[24];
    const void* e2b  = d_in[25];
    float* ws = (float*)d_ws;

    int*   flagI = (int*)(ws + 0);       // 64 reserved
    float* h     = ws + 64;              // 131072
    float* c1t   = ws + 131136;          // 393216 (c1wb bf16)
    float* w2t   = ws + 524352;          // 65536 (w2b bf16)
    float* s1t   = ws + 589888;          // 294912 (s1wb+e1wb bf16)
    float* corrB = ws + 884800;          // 65536 (corrT layout [w][n][t])
    float* tabw  = ws + 950336;          // 1536
    int*   tabd  = (int*)(ws + 951872);  // 1536
    float* t1s   = ws + 986176;          // 524288
    float* t1e   = ws + 1510464;         // 524288
    float* f     = ws + 2034752;         // 524288
    float* y     = ws + 2559040;         // 2097152
    float* w3reg = ws + 4656192;         // 4194304 (w3b + hbT bf16)
    float* Pb    = ws + 8850496;         // 8388608 (fcolb/yT scratch)
    double* gnbuf = (double*)(ws + 17239104); // 1024 doubles
    bf16*  w3b   = (bf16*)w3reg;
    bf16*  hbT   = (bf16*)(w3reg + 2097152);
    bf16*  c1wb  = (bf16*)c1t;
    bf16*  w2b   = (bf16*)w2t;
    bf16*  hwb   = (bf16*)s1t;
    bf16*  colxb = (bf16*)y;                       // y dead until apply
    bf16*  fcolb = (bf16*)Pb;                      // Pb scratch
    bf16*  yT    = (bf16*)(Pb + 4194304);          // Pb tail

    dim3 blk(256);
    dim3 blkG(1024);

    detect_k<<<dim3(1), blk, 0, stream>>>((const unsigned short*)x, flagI);

    // weight prep + table extraction
    cast_bf_k<<<dim3(1536), blk, 0, stream>>>(c1w, c1wb, 393216, flagI);
    cast_bf_k<<<dim3(576),  blk, 0, stream>>>(s1w, hwb, 147456, flagI);
    cast_bf_k<<<dim3(576),  blk, 0, stream>>>(e1w, hwb + 147456, 147456, flagI);
    cast_bf_k<<<dim3(256),  blk, 0, stream>>>(w2, w2b, 65536, flagI);
    transpose_w3b_k<<<dim3(512), blk, 0, stream>>>(w3, w3b, flagI);
    build_table_k<<<dim3(256), dim3(384), 0, stream>>>(mask, tabd, tabw, flagI);
    build_corr_k<<<dim3(256), blk, 0, stream>>>(mask, tabd, tabw, corrB, flagI);

    // conv1 via MFMA + GN1 + ReLU
    im2col_xb_k<<<dim3(3072), blk, 0, stream>>>(x, colxb, flagI);
    wgemm_mfma<1><<<dim3(16, 4, 2), blk, 0, stream>>>(
        c1wb, colxb, h, c1b, c1b, 256, 1536, 256, 1, 0L, flagI);
    gn_relu_k<<<dim3(64), blkG, 0, stream>>>(h, gn1g, gn1b, 256, 256, 32, flagI);

    // fused P-GEMM + sparse apply (taps + bias + corr -> y) + GN3 (2-phase)
    cast_hT_k<<<dim3(512), blk, 0, stream>>>(h, hbT);
    apply_y3_k<<<dim3(256), dim3(1024), 0, stream>>>(
        w3b, hbT, tabd, tabw, corrB, y, r3b, flagI);
    gn_part_k<<<dim3(512), blk, 0, stream>>>(y, gnbuf, 512, 2048, 32, 8);
    gn_apply_k<<<dim3(512), blk, 0, stream>>>(y, gnbuf, gn3g, gn3b, 512, 2048, 32, 8, flagI);

    // r2d via MFMA: cast-transpose y -> yT bf16, wgemm (bias fused) + GN2 (2-phase)
    castT_k<<<dim3(32, 8, 2), blk, 0, stream>>>(y, yT);
    wgemm_mfma<2><<<dim3(64, 2, 2), blk, 0, stream>>>(
        w2b, yT, f, r2b, r2b, 128, 512, 2048, 2, 0L, flagI);
    gn_part_k<<<dim3(256), blk, 0, stream>>>(f, gnbuf, 128, 2048, 32, 4);
    gn_apply_k<<<dim3(256), blk, 0, stream>>>(f, gnbuf, gn2g, gn2b, 128, 2048, 32, 4, flagI);

    // heads via MFMA + GN (2-phase each)
    im2col_fb_k<<<dim3(18432), blk, 0, stream>>>(f, fcolb);
    wgemm_mfma<4><<<dim3(32, 2, 4), blk, 0, stream>>>(
        hwb, fcolb, t1s, s1b, e1b, 128, 1152, 2048, 2, 147456L, flagI);
    gn_part_k<<<dim3(256), blk, 0, stream>>>(t1s, gnbuf, 128, 2048, 32, 4);
    gn_apply_k<<<dim3(256), blk, 0, stream>>>(t1s, gnbuf, sgng, sgnb, 128, 2048, 32, 4, flagI);
    gn_part_k<<<dim3(256), blk, 0, stream>>>(t1e, gnbuf, 128, 2048, 32, 4);
    gn_apply_k<<<dim3(256), blk, 0, stream>>>(t1e, gnbuf, egng, egnb, 128, 2048, 32, 4, flagI);

    // 1x1 head convs + sigmoid -> output
    head_out_k<<<dim3(64), dim3(64), 0, stream>>>(t1s, t1e, s2w, s2b, e2w, e2b, d_out, flagI);
}